// Round 6
// baseline (60.428 us; speedup 1.0000x reference)
//
#include <hip/hip_runtime.h>

// IAF inversion via incremental MADE recurrence.
// 2 rows per wave (512 single-wave blocks): weights for step d are SHARED by
// all rows, so rows/wave directly divides per-wave L2 weight traffic (R4 was
// L2-BW-bound: 128 waves/XCD x 6KB/step ~ 430cyc floor; measured 768).
// Double-buffered register prefetch (48 VGPRs) keeps total ~97 VGPR -> the
// allocator actually grants residency (R4's quad-buffer @126 need got 104).
// Masks + (-1/ln2) folded into packed weights: exp(-s) = v_exp_f32(s').
// Wave reduction via DPP row_shr/row_bcast + readlane. No LDS, no barriers.

#define Bz  1024
#define Dd  128
#define Hh  512
#define HPL 8
#define LN2 0.6931471805599453f
#define NEG_RCP_LN2 -1.4426950408889634f

typedef float v4f __attribute__((ext_vector_type(4)));

// ---------------- DPP wave-64 sum ----------------
template<int CTRL, int RMASK>
__device__ __forceinline__ float dpp_add(float v) {
    int t = __builtin_amdgcn_update_dpp(0, __float_as_int(v), CTRL, RMASK, 0xf, true);
    return v + __int_as_float(t);
}
__device__ __forceinline__ float wave_sum_bcast(float v) {
    v = dpp_add<0x111, 0xf>(v);  // row_shr:1
    v = dpp_add<0x112, 0xf>(v);  // row_shr:2
    v = dpp_add<0x114, 0xf>(v);  // row_shr:4
    v = dpp_add<0x118, 0xf>(v);  // row_shr:8
    v = dpp_add<0x142, 0xa>(v);  // row_bcast:15
    v = dpp_add<0x143, 0xc>(v);  // row_bcast:31 -> lane63 = total
    return __int_as_float(__builtin_amdgcn_readlane(__float_as_int(v), 63));
}
__device__ __forceinline__ float bcast_lane(float v, int l) {
    return __int_as_float(__builtin_amdgcn_readlane(__float_as_int(v), l));
}

// ---------------- pre-pack masked weights ----------------
// Wp[d*1536 + 0..511]     = W2[d,h]   * (m_hid<=d) * (-1/ln2)   (sigma')
// Wp[d*1536 + 512..1023]  = W2[D+d,h] * (m_hid<=d)              (mu)
// Wp[d*1536 + 1024..1535] = W1[h,d]   * (m_hid> d)              (update col)
__global__ void pack_kernel(const float* __restrict__ W1,
                            const float* __restrict__ W2,
                            float* __restrict__ Wp) {
    int idx = blockIdx.x * blockDim.x + threadIdx.x;
    if (idx >= Dd * Hh) return;
    int d = idx >> 9, h = idx & 511;
    int mh = (h % 127) + 1;
    float dot_on = (mh <= d) ? 1.f : 0.f;
    float upd_on = (mh >  d) ? 1.f : 0.f;
    float* bp = Wp + d * 1536;
    bp[h]        = W2[d * Hh + h] * dot_on * NEG_RCP_LN2;
    bp[512 + h]  = W2[(Dd + d) * Hh + h] * dot_on;
    bp[1024 + h] = W1[h * Dd + d] * upd_on;
}

// ---------------- weight buffer (24 VGPRs) ----------------
struct WBuf { v4f s0, s1, m0, m1, w0, w1; };

__device__ __forceinline__ void loadbuf(WBuf &b, const float* p) {
    b.s0 = *(const v4f*)(p);
    b.s1 = *(const v4f*)(p + 4);
    b.m0 = *(const v4f*)(p + 512);
    b.m1 = *(const v4f*)(p + 516);
    b.w0 = *(const v4f*)(p + 1024);
    b.w1 = *(const v4f*)(p + 1028);
    __builtin_amdgcn_sched_barrier(0);  // pin issue point
}

// ---------------- one step, two rows ----------------
__device__ __forceinline__ void stepR2(int d, int lane,
    float (&a0)[HPL], float (&a1)[HPL], const WBuf &w,
    float xa0, float xb0, float xa1, float xb1,
    float b2a, float b2b, float b2c, float b2d_,
    float &za0, float &zb0, float &za1, float &zb1,
    float &ld0, float &ld1)
{
    float p00 = 0.f, p01 = 0.f, q00 = 0.f, q01 = 0.f;  // row0 s',mu
    float p10 = 0.f, p11 = 0.f, q10 = 0.f, q11 = 0.f;  // row1 s',mu
#pragma unroll
    for (int k = 0; k < 4; ++k) {
        float h0 = fmaxf(a0[k], 0.f);
        float h1 = fmaxf(a1[k], 0.f);
        p00 = fmaf(h0, w.s0[k], p00);  q00 = fmaf(h0, w.m0[k], q00);
        p10 = fmaf(h1, w.s0[k], p10);  q10 = fmaf(h1, w.m0[k], q10);
    }
#pragma unroll
    for (int k = 0; k < 4; ++k) {
        float h0 = fmaxf(a0[4 + k], 0.f);
        float h1 = fmaxf(a1[4 + k], 0.f);
        p01 = fmaf(h0, w.s1[k], p01);  q01 = fmaf(h0, w.m1[k], q01);
        p11 = fmaf(h1, w.s1[k], p11);  q11 = fmaf(h1, w.m1[k], q11);
    }
    float sp0 = wave_sum_bcast(p00 + p01);
    float sm0 = wave_sum_bcast(q00 + q01);
    float sp1 = wave_sum_bcast(p10 + p11);
    float sm1 = wave_sum_bcast(q10 + q11);

    int dl = d & 63;
    float bs  = bcast_lane(d < 64 ? b2a : b2b, dl);   // scaled sigma bias
    float bm  = bcast_lane(d < 64 ? b2c : b2d_, dl);  // mu bias
    float xv0 = bcast_lane(d < 64 ? xa0 : xb0, dl);
    float xv1 = bcast_lane(d < 64 ? xa1 : xb1, dl);

    float s0 = sp0 + bs, s1 = sp1 + bs;   // s' = -s/ln2
    float m0 = sm0 + bm, m1 = sm1 + bm;
    float e0 = __builtin_amdgcn_exp2f(s0);  // exp(-s) = 2^{s'}
    float e1 = __builtin_amdgcn_exp2f(s1);
    float zd0 = (xv0 - m0) * e0;
    float zd1 = (xv1 - m1) * e1;
    ld0 += s0;                             // ld' = sum s'; final ld = ln2*ld'
    ld1 += s1;
    if (dl == lane) {
        if (d < 64) { za0 = zd0; za1 = zd1; }
        else        { zb0 = zd0; zb1 = zd1; }
    }
#pragma unroll
    for (int k = 0; k < 4; ++k) {
        a0[k] = fmaf(zd0, w.w0[k], a0[k]);
        a1[k] = fmaf(zd1, w.w0[k], a1[k]);
    }
#pragma unroll
    for (int k = 0; k < 4; ++k) {
        a0[4 + k] = fmaf(zd0, w.w1[k], a0[4 + k]);
        a1[4 + k] = fmaf(zd1, w.w1[k], a1[4 + k]);
    }
}

__global__ __launch_bounds__(64, 1) void iaf5_kernel(
    const float* __restrict__ x,
    const float* __restrict__ b1,
    const float* __restrict__ b2,
    const float* __restrict__ Wp,
    float* __restrict__ out)
{
    const int lane = (int)threadIdx.x;
    const int r0   = (int)blockIdx.x * 2;
    const int r1   = r0 + 1;
    const int h0   = lane * HPL;

    float a0[HPL], a1[HPL];
    {
        float4 t0 = *(const float4*)(b1 + h0);
        float4 t1 = *(const float4*)(b1 + h0 + 4);
        a0[0]=t0.x; a0[1]=t0.y; a0[2]=t0.z; a0[3]=t0.w;
        a0[4]=t1.x; a0[5]=t1.y; a0[6]=t1.z; a0[7]=t1.w;
#pragma unroll
        for (int k = 0; k < HPL; ++k) a1[k] = a0[k];
    }
    float xa0 = x[r0 * Dd + lane],      xb0 = x[r0 * Dd + 64 + lane];
    float xa1 = x[r1 * Dd + lane],      xb1 = x[r1 * Dd + 64 + lane];
    float b2a = b2[lane] * NEG_RCP_LN2;
    float b2b = b2[64 + lane] * NEG_RCP_LN2;
    float b2c = b2[128 + lane],         b2d_ = b2[192 + lane];

    float za0 = 0.f, zb0 = 0.f, za1 = 0.f, zb1 = 0.f;
    float ld0 = 0.f, ld1 = 0.f;

    const float* base = Wp + h0;
    WBuf A, B;
    loadbuf(A, base);
    loadbuf(B, base + 1536);

#pragma unroll 1
    for (int t = 0; t < Dd; t += 2) {
        stepR2(t, lane, a0, a1, A, xa0, xb0, xa1, xb1,
               b2a, b2b, b2c, b2d_, za0, zb0, za1, zb1, ld0, ld1);
        loadbuf(A, base + (size_t)((t + 2 < Dd) ? (t + 2) : 0) * 1536);
        stepR2(t + 1, lane, a0, a1, B, xa0, xb0, xa1, xb1,
               b2a, b2b, b2c, b2d_, za0, zb0, za1, zb1, ld0, ld1);
        loadbuf(B, base + (size_t)((t + 3 < Dd) ? (t + 3) : 1) * 1536);
    }

    out[r0 * Dd + lane]      = za0;
    out[r0 * Dd + 64 + lane] = zb0;
    out[r1 * Dd + lane]      = za1;
    out[r1 * Dd + 64 + lane] = zb1;
    if (lane == 0) {
        out[Bz * Dd + r0] = LN2 * ld0;
        out[Bz * Dd + r1] = LN2 * ld1;
    }
}

// ---------------- fallback (ws too small): masked direct loads ----------------
__global__ __launch_bounds__(64, 1) void iaf_fb_kernel(
    const float* __restrict__ x,  const float* __restrict__ W1,
    const float* __restrict__ b1, const float* __restrict__ W2,
    const float* __restrict__ b2, float* __restrict__ out)
{
    const int lane = (int)threadIdx.x;
    const int row  = (int)blockIdx.x;
    const int h0   = lane * HPL;
    float a[HPL]; int mh[HPL];
#pragma unroll
    for (int k = 0; k < HPL; ++k) { a[k] = b1[h0 + k]; mh[k] = ((h0 + k) % 127) + 1; }
    float xa  = x[row * Dd + lane], xb = x[row * Dd + 64 + lane];
    float b2a = b2[lane], b2b = b2[64 + lane], b2c = b2[128 + lane], b2d_ = b2[192 + lane];
    float za = 0.f, zb = 0.f, ld = 0.f;
    for (int d = 0; d < Dd; ++d) {
        float ps = 0.f, pm = 0.f;
#pragma unroll
        for (int k = 0; k < HPL; ++k) {
            float h = fmaxf(a[k], 0.f);
            h = (mh[k] <= d) ? h : 0.f;
            ps = fmaf(h, W2[d * Hh + h0 + k], ps);
            pm = fmaf(h, W2[(Dd + d) * Hh + h0 + k], pm);
        }
        ps = wave_sum_bcast(ps);
        pm = wave_sum_bcast(pm);
        int dl = d & 63;
        float sd = ps + bcast_lane(d < 64 ? b2a : b2b, dl);
        float md = pm + bcast_lane(d < 64 ? b2c : b2d_, dl);
        float xv =      bcast_lane(d < 64 ? xa  : xb,  dl);
        float zd = (xv - md) * __expf(-sd);
        ld -= sd;
        if (dl == lane) { if (d < 64) za = zd; else zb = zd; }
#pragma unroll
        for (int k = 0; k < HPL; ++k)
            if (d < mh[k]) a[k] = fmaf(zd, W1[(h0 + k) * Dd + d], a[k]);
    }
    out[row * Dd + lane]      = za;
    out[row * Dd + 64 + lane] = zb;
    if (lane == 0) out[Bz * Dd + row] = ld;
}

extern "C" void kernel_launch(void* const* d_in, const int* in_sizes, int n_in,
                              void* d_out, int out_size, void* d_ws, size_t ws_size,
                              hipStream_t stream) {
    const float* x  = (const float*)d_in[0];
    const float* W1 = (const float*)d_in[1];
    const float* b1 = (const float*)d_in[2];
    const float* W2 = (const float*)d_in[3];
    const float* b2 = (const float*)d_in[4];
    float* out = (float*)d_out;
    float* Wp  = (float*)d_ws;

    const size_t need = (size_t)Dd * 1536 * sizeof(float);  // 768 KB
    if (ws_size >= need) {
        pack_kernel<<<(Dd * Hh + 255) / 256, 256, 0, stream>>>(W1, W2, Wp);
        iaf5_kernel<<<Bz / 2, 64, 0, stream>>>(x, b1, b2, Wp, out);
    } else {
        iaf_fb_kernel<<<Bz, 64, 0, stream>>>(x, W1, b1, W2, b2, out);
    }
}

// Round 7
// 53.152 us; speedup vs baseline: 1.1369x; 1.1369x over previous
//
#include <hip/hip_runtime.h>
#include <stdint.h>

// IAF inversion via incremental MADE recurrence.
// 1 row per wave, 1024 single-wave blocks = 1 wave/SIMD chip-wide.
// Weight prefetch via global_load_lds (NO register destination -> the RA
// cannot sink it; R2/R4/R5 all lost register-prefetch to the allocator).
// 4-deep LDS slot pipeline, counted s_waitcnt vmcnt(18) per step.
// Pack layout XOR-swizzled so ds_read_b128 is 2-way/bank (free, m136).
// DPP wave reduction; exp(-s)=2^(s') with -1/ln2 folded into weights.

#define Bz  1024
#define Dd  128
#define Hh  512
#define LN2 0.6931471805599453f
#define NRL -1.4426950408889634f   // -1/ln2

typedef float v4f __attribute__((ext_vector_type(4)));
typedef const __attribute__((address_space(1))) uint32_t* gas_t;
typedef __attribute__((address_space(3))) uint32_t* las_t;

// ---------------- DPP wave-64 sum ----------------
template<int CTRL, int RMASK>
__device__ __forceinline__ float dpp_add(float v) {
    int t = __builtin_amdgcn_update_dpp(0, __float_as_int(v), CTRL, RMASK, 0xf, true);
    return v + __int_as_float(t);
}
__device__ __forceinline__ float wave_sum_bcast(float v) {
    v = dpp_add<0x111, 0xf>(v);  // row_shr:1
    v = dpp_add<0x112, 0xf>(v);  // row_shr:2
    v = dpp_add<0x114, 0xf>(v);  // row_shr:4
    v = dpp_add<0x118, 0xf>(v);  // row_shr:8
    v = dpp_add<0x142, 0xa>(v);  // row_bcast:15
    v = dpp_add<0x143, 0xc>(v);  // row_bcast:31 -> lane63 = total
    return __int_as_float(__builtin_amdgcn_readlane(__float_as_int(v), 63));
}
__device__ __forceinline__ float bcast_lane(float v, int l) {
    return __int_as_float(__builtin_amdgcn_readlane(__float_as_int(v), l));
}

// ---------------- pre-pack masked weights, bank-swizzled ----------------
// Logical per-step layout (1536 floats): [0..511]=W2sig*mask*(-1/ln2),
// [512..1023]=W2mu*mask, [1024..1535]=W1col*mask.
// 16B-chunk swizzle within each 512-float segment: chunk c -> position
// (c&~1) | ((c&1)^((c>>3)&1)).  Reader (lane l) uses the same XOR, so
// each ds_read_b128 instruction hits every bank-group exactly twice.
__global__ void pack_kernel(const float* __restrict__ W1,
                            const float* __restrict__ W2,
                            float* __restrict__ Wp) {
    int idx = blockIdx.x * blockDim.x + threadIdx.x;
    if (idx >= Dd * 1536) return;
    int d = idx / 1536, f = idx % 1536;
    int seg = f >> 9, h = f & 511;
    int mh = (h % 127) + 1;
    float v;
    if (seg == 0)      v = W2[d * Hh + h]        * ((mh <= d) ? NRL : 0.f);
    else if (seg == 1) v = W2[(Dd + d) * Hh + h] * ((mh <= d) ? 1.f : 0.f);
    else               v = W1[h * Dd + d]        * ((mh >  d) ? 1.f : 0.f);
    int c = (f >> 2) & 127, e = f & 3;
    int pos = (seg << 7) + (c & ~1) + ((c & 1) ^ ((c >> 3) & 1));
    Wp[d * 1536 + pos * 4 + e] = v;
}

__global__ __launch_bounds__(64, 1) void iaf6_kernel(
    const float* __restrict__ x,
    const float* __restrict__ b1,
    const float* __restrict__ b2,
    const float* __restrict__ Wp,
    float* __restrict__ out)
{
    __shared__ float lds[4 * 1536];           // 24 KB: 4 pipeline slots
    const int lane = (int)threadIdx.x;
    const int row  = (int)blockIdx.x;
    const int h0   = lane * 8;

    // ---- row state: preactivations, x, biases (pinned before staging) ----
    float a[8];
    {
        float4 t0 = *(const float4*)(b1 + h0);
        float4 t1 = *(const float4*)(b1 + h0 + 4);
        a[0]=t0.x; a[1]=t0.y; a[2]=t0.z; a[3]=t0.w;
        a[4]=t1.x; a[5]=t1.y; a[6]=t1.z; a[7]=t1.w;
    }
    float xa  = x[row * Dd + lane];
    float xb  = x[row * Dd + 64 + lane];
    float b2a = b2[lane] * NRL,        b2b = b2[64 + lane] * NRL;
    float b2c = b2[128 + lane],        b2d_ = b2[192 + lane];
    // Force materialization here so no waitcnt for these lands in the loop.
    asm volatile("" : "+v"(xa), "+v"(xb), "+v"(b2a), "+v"(b2b), "+v"(b2c),
                      "+v"(b2d_), "+v"(a[0]), "+v"(a[1]), "+v"(a[2]),
                      "+v"(a[3]), "+v"(a[4]), "+v"(a[5]), "+v"(a[6]), "+v"(a[7]));

    // ---- async stage: 6 x 1KB global->LDS for step t into slot t&3 ----
    auto stage = [&](int t) {
        const float* g = Wp + (size_t)t * 1536 + lane * 4;  // per-lane 16B
        float* lb = lds + (t & 3) * 1536;                   // uniform base
#pragma unroll
        for (int i = 0; i < 6; ++i)
            __builtin_amdgcn_global_load_lds((gas_t)(g + i * 256),
                                             (las_t)(lb + i * 256), 16, 0, 0);
    };

    stage(0); stage(1); stage(2); stage(3);   // 24 loads outstanding

    float za = 0.f, zb = 0.f, ldet = 0.f;
    const int bit = (lane >> 2) & 1;
    const int p0  = 2 * lane + bit;           // swizzled chunk addr, j=0
    const int p1  = 2 * lane + 1 - bit;       // swizzled chunk addr, j=1

#pragma unroll 1
    for (int t = 0; t < Dd; ++t) {
        // step t's 6 loads retired; 18 (steps t+1..t+3) still in flight
        asm volatile("s_waitcnt vmcnt(18)" ::: "memory");
        __builtin_amdgcn_sched_barrier(0);

        const v4f* lp = (const v4f*)(lds + (t & 3) * 1536);
        v4f s0 = lp[p0],       s1 = lp[p1];
        v4f m0 = lp[128 + p0], m1 = lp[128 + p1];
        v4f w0 = lp[256 + p0], w1 = lp[256 + p1];

        float ps0 = 0.f, ps1 = 0.f, pm0 = 0.f, pm1 = 0.f;
#pragma unroll
        for (int k = 0; k < 4; ++k) {
            float hv = fmaxf(a[k], 0.f);
            ps0 = fmaf(hv, s0[k], ps0);
            pm0 = fmaf(hv, m0[k], pm0);
        }
#pragma unroll
        for (int k = 0; k < 4; ++k) {
            float hv = fmaxf(a[4 + k], 0.f);
            ps1 = fmaf(hv, s1[k], ps1);
            pm1 = fmaf(hv, m1[k], pm1);
        }
        float sp = wave_sum_bcast(ps0 + ps1);   // s' (pre-bias)
        float sm = wave_sum_bcast(pm0 + pm1);   // mu (pre-bias)

        int dl = t & 63;
        float bs = bcast_lane(t < 64 ? b2a : b2b, dl);
        float bm = bcast_lane(t < 64 ? b2c : b2d_, dl);
        float xv = bcast_lane(t < 64 ? xa  : xb,  dl);

        float sd = sp + bs;                      // s' = -s/ln2
        float zd = (xv - (sm + bm)) * __builtin_amdgcn_exp2f(sd);
        ldet += sd;
        if (dl == lane) { if (t < 64) za = zd; else zb = zd; }

#pragma unroll
        for (int k = 0; k < 4; ++k) a[k]     = fmaf(zd, w0[k], a[k]);
#pragma unroll
        for (int k = 0; k < 4; ++k) a[4 + k] = fmaf(zd, w1[k], a[4 + k]);

        // re-stage this slot for step t+4 (after all ds_reads retired)
        __builtin_amdgcn_sched_barrier(0);
        asm volatile("s_waitcnt lgkmcnt(0)" ::: "memory");
        if (t < Dd - 4) stage(t + 4);
    }

    out[row * Dd + lane]      = za;
    out[row * Dd + 64 + lane] = zb;
    if (lane == 0) out[Bz * Dd + row] = LN2 * ldet;
}

// ---------------- fallback (ws too small): masked direct loads ----------------
__global__ __launch_bounds__(64, 1) void iaf_fb_kernel(
    const float* __restrict__ x,  const float* __restrict__ W1,
    const float* __restrict__ b1, const float* __restrict__ W2,
    const float* __restrict__ b2, float* __restrict__ out)
{
    const int lane = (int)threadIdx.x;
    const int row  = (int)blockIdx.x;
    const int h0   = lane * 8;
    float a[8]; int mh[8];
#pragma unroll
    for (int k = 0; k < 8; ++k) { a[k] = b1[h0 + k]; mh[k] = ((h0 + k) % 127) + 1; }
    float xa  = x[row * Dd + lane], xb = x[row * Dd + 64 + lane];
    float b2a = b2[lane], b2b = b2[64 + lane], b2c = b2[128 + lane], b2d_ = b2[192 + lane];
    float za = 0.f, zb = 0.f, ld = 0.f;
    for (int d = 0; d < Dd; ++d) {
        float ps = 0.f, pm = 0.f;
#pragma unroll
        for (int k = 0; k < 8; ++k) {
            float h = fmaxf(a[k], 0.f);
            h = (mh[k] <= d) ? h : 0.f;
            ps = fmaf(h, W2[d * Hh + h0 + k], ps);
            pm = fmaf(h, W2[(Dd + d) * Hh + h0 + k], pm);
        }
        ps = wave_sum_bcast(ps);
        pm = wave_sum_bcast(pm);
        int dl = d & 63;
        float sd = ps + bcast_lane(d < 64 ? b2a : b2b, dl);
        float md = pm + bcast_lane(d < 64 ? b2c : b2d_, dl);
        float xv =      bcast_lane(d < 64 ? xa  : xb,  dl);
        float zd = (xv - md) * __expf(-sd);
        ld -= sd;
        if (dl == lane) { if (d < 64) za = zd; else zb = zd; }
#pragma unroll
        for (int k = 0; k < 8; ++k)
            if (d < mh[k]) a[k] = fmaf(zd, W1[(h0 + k) * Dd + d], a[k]);
    }
    out[row * Dd + lane]      = za;
    out[row * Dd + 64 + lane] = zb;
    if (lane == 0) out[Bz * Dd + row] = ld;
}

extern "C" void kernel_launch(void* const* d_in, const int* in_sizes, int n_in,
                              void* d_out, int out_size, void* d_ws, size_t ws_size,
                              hipStream_t stream) {
    const float* x  = (const float*)d_in[0];
    const float* W1 = (const float*)d_in[1];
    const float* b1 = (const float*)d_in[2];
    const float* W2 = (const float*)d_in[3];
    const float* b2 = (const float*)d_in[4];
    float* out = (float*)d_out;
    float* Wp  = (float*)d_ws;

    const size_t need = (size_t)Dd * 1536 * sizeof(float);  // 768 KB
    if (ws_size >= need) {
        pack_kernel<<<(Dd * 1536 + 255) / 256, 256, 0, stream>>>(W1, W2, Wp);
        iaf6_kernel<<<Bz, 64, 0, stream>>>(x, b1, b2, Wp, out);
    } else {
        iaf_fb_kernel<<<Bz, 64, 0, stream>>>(x, W1, b1, W2, b2, out);
    }
}

// Round 8
// 50.543 us; speedup vs baseline: 1.1956x; 1.0516x over previous
//
#include <hip/hip_runtime.h>
#include <stdint.h>

// IAF inversion via incremental MADE recurrence.
// 256 blocks x 4 waves (1 block/CU), 1 row per wave. The per-step packed
// weights (6KB) are staged ONCE per block into a 4-slot LDS pipeline:
// wave w stages steps == w (mod 4) into slot w via global_load_lds.
// Sync: per step only the stager-of-step-(u+1) drains vmcnt(0) (issued
// ~3 steps earlier -> free) before ONE raw s_barrier. LDS->reg double
// buffer one step ahead (compile-time slots via 4x unroll) hides ds_read
// latency. Pack layout swizzled G = g ^ ((g>>3)&7) so each ds_read_b128
// hits all 8 LDS bank-groups exactly 8x (even) -> zero conflicts.
// DPP wave reduction; exp(-s) = 2^(s') with -1/ln2 folded into weights.

#define Bz  1024
#define Dd  128
#define Hh  512
#define LN2 0.6931471805599453f
#define NRL -1.4426950408889634f   // -1/ln2

typedef float v4f __attribute__((ext_vector_type(4)));
typedef const __attribute__((address_space(1))) uint32_t* gas_t;
typedef __attribute__((address_space(3))) uint32_t* las_t;

// ---------------- DPP wave-64 sum ----------------
template<int CTRL, int RMASK>
__device__ __forceinline__ float dpp_add(float v) {
    int t = __builtin_amdgcn_update_dpp(0, __float_as_int(v), CTRL, RMASK, 0xf, true);
    return v + __int_as_float(t);
}
__device__ __forceinline__ float wave_sum_bcast(float v) {
    v = dpp_add<0x111, 0xf>(v);  // row_shr:1
    v = dpp_add<0x112, 0xf>(v);  // row_shr:2
    v = dpp_add<0x114, 0xf>(v);  // row_shr:4
    v = dpp_add<0x118, 0xf>(v);  // row_shr:8
    v = dpp_add<0x142, 0xa>(v);  // row_bcast:15
    v = dpp_add<0x143, 0xc>(v);  // row_bcast:31 -> lane63 = total
    return __int_as_float(__builtin_amdgcn_readlane(__float_as_int(v), 63));
}
__device__ __forceinline__ float bcast_lane(float v, int l) {
    return __int_as_float(__builtin_amdgcn_readlane(__float_as_int(v), l));
}

// ---------------- pre-pack masked weights, bank-even swizzle ----------------
// Logical per-step floats f in [0,1536): seg=f>>9 (0:sigma',1:mu,2:w1col),
// h=f&511. 16B-granule index g=(f>>2)&127 stored at G = g ^ ((g>>3)&7)
// (involution). Reader lane l uses G0=swz(2l), G1=swz(2l+1): each
// ds_read_b128 then hits every 16B bank-group exactly 8 times (even).
__global__ void pack_kernel(const float* __restrict__ W1,
                            const float* __restrict__ W2,
                            float* __restrict__ Wp) {
    int idx = blockIdx.x * blockDim.x + threadIdx.x;
    if (idx >= Dd * 1536) return;
    int d = idx / 1536, f = idx % 1536;
    int seg = f >> 9, h = f & 511;
    int mh = (h % 127) + 1;
    float v;
    if (seg == 0)      v = W2[d * Hh + h]        * ((mh <= d) ? NRL : 0.f);
    else if (seg == 1) v = W2[(Dd + d) * Hh + h] * ((mh <= d) ? 1.f : 0.f);
    else               v = W1[h * Dd + d]        * ((mh >  d) ? 1.f : 0.f);
    int g = (f >> 2) & 127, e = f & 3;
    int G = g ^ ((g >> 3) & 7);
    Wp[d * 1536 + (seg << 9) + G * 4 + e] = v;
}

// ---------------- stage 6KB (one step) global -> LDS slot ----------------
__device__ __forceinline__ void stage6(const float* g, float* l) {
#pragma unroll
    for (int i = 0; i < 6; ++i)
        __builtin_amdgcn_global_load_lds((gas_t)(g + i * 256),
                                         (las_t)(l + i * 256), 16, 0, 0);
}

struct WB { v4f s0, s1, m0, m1, w0, w1; };

// ---------------- one recurrence step (weights already in regs) ----------
__device__ __forceinline__ void computeStep(int u, int lane, const WB& w,
    float (&a)[8], float xa, float xb,
    float b2a, float b2b, float b2c, float b2d_,
    float &za, float &zb, float &ldet)
{
    float ps0 = 0.f, ps1 = 0.f, pm0 = 0.f, pm1 = 0.f;
#pragma unroll
    for (int k = 0; k < 4; ++k) {
        float hv = fmaxf(a[k], 0.f);
        ps0 = fmaf(hv, w.s0[k], ps0);
        pm0 = fmaf(hv, w.m0[k], pm0);
    }
#pragma unroll
    for (int k = 0; k < 4; ++k) {
        float hv = fmaxf(a[4 + k], 0.f);
        ps1 = fmaf(hv, w.s1[k], ps1);
        pm1 = fmaf(hv, w.m1[k], pm1);
    }
    float sp = wave_sum_bcast(ps0 + ps1);   // s' (pre-bias, = -s/ln2 part)
    float sm = wave_sum_bcast(pm0 + pm1);   // mu (pre-bias)

    int dl = u & 63;
    float bs = bcast_lane(u < 64 ? b2a : b2b, dl);
    float bm = bcast_lane(u < 64 ? b2c : b2d_, dl);
    float xv = bcast_lane(u < 64 ? xa  : xb,  dl);

    float sd = sp + bs;                       // s' = -s/ln2
    float zd = (xv - (sm + bm)) * __builtin_amdgcn_exp2f(sd);
    ldet += sd;
    if (dl == lane) { if (u < 64) za = zd; else zb = zd; }

#pragma unroll
    for (int k = 0; k < 4; ++k) a[k]     = fmaf(zd, w.w0[k], a[k]);
#pragma unroll
    for (int k = 0; k < 4; ++k) a[4 + k] = fmaf(zd, w.w1[k], a[4 + k]);
}

__global__ __launch_bounds__(256, 1) void iaf7_kernel(
    const float* __restrict__ x,
    const float* __restrict__ b1,
    const float* __restrict__ b2,
    const float* __restrict__ Wp,
    float* __restrict__ out)
{
    __shared__ float lds[4 * 1536];            // 24 KB: 4 pipeline slots
    const int tid  = (int)threadIdx.x;
    const int lane = tid & 63;
    const int wid  = tid >> 6;                 // wave id 0..3
    const int row  = (int)blockIdx.x * 4 + wid;
    const int h0   = lane * 8;

    // ---- per-row state ----
    float a[8];
    {
        float4 t0 = *(const float4*)(b1 + h0);
        float4 t1 = *(const float4*)(b1 + h0 + 4);
        a[0]=t0.x; a[1]=t0.y; a[2]=t0.z; a[3]=t0.w;
        a[4]=t1.x; a[5]=t1.y; a[6]=t1.z; a[7]=t1.w;
    }
    float xa  = x[row * Dd + lane];
    float xb  = x[row * Dd + 64 + lane];
    float b2a = b2[lane] * NRL,  b2b = b2[64 + lane] * NRL;
    float b2c = b2[128 + lane],  b2d_ = b2[192 + lane];
    asm volatile("" : "+v"(xa), "+v"(xb), "+v"(b2a), "+v"(b2b), "+v"(b2c),
                      "+v"(b2d_), "+v"(a[0]), "+v"(a[1]), "+v"(a[2]),
                      "+v"(a[3]), "+v"(a[4]), "+v"(a[5]), "+v"(a[6]), "+v"(a[7]));

    float* myslot = lds + wid * 1536;          // wave w owns slot w

    // ---- prologue: waves 0..2 stage steps 0..2; wave 3 stages step 3 in-loop
    if (wid < 3) stage6(Wp + (size_t)wid * 1536 + lane * 4, myslot);
    const int nxt = (wid == 3) ? 3 : (wid + 4);   // wave's next step to stage
    const float* gp = Wp + (size_t)nxt * 1536 + lane * 4;

    asm volatile("s_waitcnt vmcnt(0)" ::: "memory");
    __builtin_amdgcn_sched_barrier(0);
    __builtin_amdgcn_s_barrier();
    __builtin_amdgcn_sched_barrier(0);

    // ---- swizzled reader addresses (lane constants) ----
    const int g0 = 2 * lane, g1 = 2 * lane + 1;
    const int G0 = g0 ^ ((g0 >> 3) & 7);
    const int G1 = g1 ^ ((g1 >> 3) & 7);
    const v4f* lv = (const v4f*)lds;

    float za = 0.f, zb = 0.f, ldet = 0.f;

#define PREF(SLOT, BUF) do {                                          \
        BUF.s0 = lv[(SLOT) * 384 +       G0];                         \
        BUF.s1 = lv[(SLOT) * 384 +       G1];                         \
        BUF.m0 = lv[(SLOT) * 384 + 128 + G0];                         \
        BUF.m1 = lv[(SLOT) * 384 + 128 + G1];                         \
        BUF.w0 = lv[(SLOT) * 384 + 256 + G0];                         \
        BUF.w1 = lv[(SLOT) * 384 + 256 + G1];                         \
    } while (0)

    WB P, Q;
    PREF(0, P);                                  // step 0 -> P

#define SUB(C, CUR, NXT) do {                                         \
        const int u = t0 + (C);                                       \
        if (wid == (((C) + 1) & 3))                                   \
            asm volatile("s_waitcnt vmcnt(0)" ::: "memory");          \
        __builtin_amdgcn_sched_barrier(0);                            \
        __builtin_amdgcn_s_barrier();                                 \
        __builtin_amdgcn_sched_barrier(0);                            \
        if (wid == (((C) + 3) & 3) && u + 3 < Dd) {                   \
            stage6(gp, myslot);                                       \
            gp += 4 * 1536;                                           \
        }                                                             \
        __builtin_amdgcn_sched_barrier(0);                            \
        PREF(((C) + 1) & 3, NXT);                                     \
        computeStep(u, lane, CUR, a, xa, xb, b2a, b2b, b2c, b2d_,     \
                    za, zb, ldet);                                    \
    } while (0)

#pragma unroll 1
    for (int t0 = 0; t0 < Dd; t0 += 4) {
        SUB(0, P, Q);
        SUB(1, Q, P);
        SUB(2, P, Q);
        SUB(3, Q, P);
    }
#undef SUB
#undef PREF

    out[row * Dd + lane]      = za;
    out[row * Dd + 64 + lane] = zb;
    if (lane == 0) out[Bz * Dd + row] = LN2 * ldet;
}

// ---------------- fallback (ws too small): masked direct loads ----------------
__global__ __launch_bounds__(64, 1) void iaf_fb_kernel(
    const float* __restrict__ x,  const float* __restrict__ W1,
    const float* __restrict__ b1, const float* __restrict__ W2,
    const float* __restrict__ b2, float* __restrict__ out)
{
    const int lane = (int)threadIdx.x;
    const int row  = (int)blockIdx.x;
    const int h0   = lane * 8;
    float a[8]; int mh[8];
#pragma unroll
    for (int k = 0; k < 8; ++k) { a[k] = b1[h0 + k]; mh[k] = ((h0 + k) % 127) + 1; }
    float xa  = x[row * Dd + lane], xb = x[row * Dd + 64 + lane];
    float b2a = b2[lane], b2b = b2[64 + lane], b2c = b2[128 + lane], b2d_ = b2[192 + lane];
    float za = 0.f, zb = 0.f, ld = 0.f;
    for (int d = 0; d < Dd; ++d) {
        float ps = 0.f, pm = 0.f;
#pragma unroll
        for (int k = 0; k < 8; ++k) {
            float h = fmaxf(a[k], 0.f);
            h = (mh[k] <= d) ? h : 0.f;
            ps = fmaf(h, W2[d * Hh + h0 + k], ps);
            pm = fmaf(h, W2[(Dd + d) * Hh + h0 + k], pm);
        }
        ps = wave_sum_bcast(ps);
        pm = wave_sum_bcast(pm);
        int dl = d & 63;
        float sd = ps + bcast_lane(d < 64 ? b2a : b2b, dl);
        float md = pm + bcast_lane(d < 64 ? b2c : b2d_, dl);
        float xv =      bcast_lane(d < 64 ? xa  : xb,  dl);
        float zd = (xv - md) * __expf(-sd);
        ld -= sd;
        if (dl == lane) { if (d < 64) za = zd; else zb = zd; }
#pragma unroll
        for (int k = 0; k < 8; ++k)
            if (d < mh[k]) a[k] = fmaf(zd, W1[(h0 + k) * Dd + d], a[k]);
    }
    out[row * Dd + lane]      = za;
    out[row * Dd + 64 + lane] = zb;
    if (lane == 0) out[Bz * Dd + row] = ld;
}

extern "C" void kernel_launch(void* const* d_in, const int* in_sizes, int n_in,
                              void* d_out, int out_size, void* d_ws, size_t ws_size,
                              hipStream_t stream) {
    const float* x  = (const float*)d_in[0];
    const float* W1 = (const float*)d_in[1];
    const float* b1 = (const float*)d_in[2];
    const float* W2 = (const float*)d_in[3];
    const float* b2 = (const float*)d_in[4];
    float* out = (float*)d_out;
    float* Wp  = (float*)d_ws;

    const size_t need = (size_t)Dd * 1536 * sizeof(float);  // 768 KB
    if (ws_size >= need) {
        pack_kernel<<<(Dd * 1536 + 255) / 256, 256, 0, stream>>>(W1, W2, Wp);
        iaf7_kernel<<<Bz / 4, 256, 0, stream>>>(x, b1, b2, Wp, out);
    } else {
        iaf_fb_kernel<<<Bz, 64, 0, stream>>>(x, W1, b1, W2, b2, out);
    }
}